// Round 10
// baseline (171.010 us; speedup 1.0000x reference)
//
#include <hip/hip_runtime.h>
#include <hip/hip_fp16.h>

constexpr int N = 50000;        // nodes
constexpr int D = 64;           // feature dim
constexpr int E = 1600000;      // edges
constexpr int NBUCK = (N + 127) / 128;   // 391 buckets of 128 nodes (dst>>7)
constexpr int CAP = 4608;                // bucket window capacity (mean 4092)
constexpr int BTHREADS = 1024;
constexpr int BBLOCKS = 256;             // verified round-7 config
constexpr int EPB = E / BBLOCKS;         // 6250 edges per block (exact)
constexpr int CPT = (EPB + BTHREADS - 1) / BTHREADS;  // 7

// ---------------------------------------------------------------------------
// K0: init per-bucket window cursors (cursor[b] = b*CAP)
__global__ void k_init(int* __restrict__ cursor) {
    int t = threadIdx.x;
    if (t < NBUCK) cursor[t] = t * CAP;
}

// K1: privatized counting-sort scatter -> fixed-capacity bucket windows.
// packed = dst<<16 | src (both < 65536); bucket = packed>>23.
// (verified round-7 version, unchanged)
__global__ __launch_bounds__(1024)
void k_bucket(const int* __restrict__ src, const int* __restrict__ dst,
              int* __restrict__ cursor, unsigned* __restrict__ packed) {
    __shared__ int lh[NBUCK];
    __shared__ int scanI[NBUCK];         // inclusive prefix over buckets
    __shared__ int wsum[16];             // 16 waves
    __shared__ int lb[NBUCK];
    __shared__ unsigned stage[EPB];      // 25 KB
    int tid = threadIdx.x;
    if (tid < NBUCK) lh[tid] = 0;
    __syncthreads();
    int base_e = blockIdx.x * EPB;
    unsigned pk[CPT];
    int bn[CPT], rk[CPT];
#pragma unroll
    for (int i = 0; i < CPT; ++i) {
        int idx = i * BTHREADS + tid;
        if (idx < EPB) {
            int e = base_e + idx;
            int d = dst[e];
            int s = src[e];
            bn[i] = d >> 7;
            pk[i] = ((unsigned)d << 16) | (unsigned)s;
            rk[i] = atomicAdd(&lh[bn[i]], 1);
        } else bn[i] = -1;
    }
    __syncthreads();
    // hierarchical inclusive scan of lh[0..NBUCK) into scanI
    int w = tid >> 6, l = tid & 63;
    int v = (tid < NBUCK) ? lh[tid] : 0;
    for (int off = 1; off < 64; off <<= 1) {
        int t = __shfl_up(v, off, 64);
        if (l >= off) v += t;
    }
    if (tid < NBUCK) scanI[tid] = v;
    if (l == 63) wsum[w] = v;
    __syncthreads();
    if (tid < 64) {                      // wave 0 scans the 16 wave sums
        int s = (tid < 16) ? wsum[tid] : 0;
        for (int off = 1; off < 16; off <<= 1) {
            int t = __shfl_up(s, off, 64);
            if (tid >= off) s += t;
        }
        if (tid < 16) wsum[tid] = s;
    }
    __syncthreads();
    if (tid < NBUCK && w > 0) scanI[tid] += wsum[w - 1];
    if (tid < NBUCK) {
        int c = lh[tid];
        lb[tid] = c ? atomicAdd(&cursor[tid], c) : 0;   // one global atomic/bucket/block
    }
    __syncthreads();
#pragma unroll
    for (int i = 0; i < CPT; ++i) {
        if (bn[i] >= 0) {
            int eb = (bn[i] == 0) ? 0 : scanI[bn[i] - 1];
            stage[eb + rk[i]] = pk[i];   // LDS scatter into bucket-sorted order
        }
    }
    __syncthreads();
    for (int j = tid; j < EPB; j += BTHREADS) {
        unsigned vv = stage[j];
        int bk = vv >> 23;               // dst>>7
        int eb = (bk == 0) ? 0 : scanI[bk - 1];
        packed[lb[bk] + (j - eb)] = vv;  // contiguous within each chunk
    }
}

// K2 (single-pass CSR): rank from the histogram atomicAdd IS the stable slot.
// (verified round-7 version, unchanged)
__global__ __launch_bounds__(1024)
void k_csr(const int* __restrict__ cursor, const unsigned* __restrict__ packed,
           unsigned short* __restrict__ csr, int* __restrict__ rowptr,
           int* __restrict__ rowend, float* __restrict__ norm) {
    __shared__ int cnt[128];
    __shared__ int rowoff[128];          // exclusive prefix over 128 bins
    __shared__ unsigned short stage[CAP];   // 9 KB node-sorted src list
    int b = blockIdx.x, tid = threadIdx.x;
    if (tid < 128) cnt[tid] = 0;
    __syncthreads();
    int beg = b * CAP;
    int m = cursor[b] - beg;             // edges in this bucket (<= CAP)
    unsigned pk[5];
    int rk[5], dd[5];
#pragma unroll
    for (int it = 0; it < 5; ++it) {     // ceil(CAP/1024) = 5
        int j = it * 1024 + tid;
        if (j < m) {
            unsigned p = packed[beg + j];
            int d = (p >> 16) & 127;
            dd[it] = d;
            pk[it] = p;
            rk[it] = atomicAdd(&cnt[d], 1);   // rank = stable slot
        } else dd[it] = -1;
    }
    __syncthreads();
    if (tid < 64) {                      // wave 0: 2 bins/lane inclusive scan
        int a = cnt[2 * tid], c1 = cnt[2 * tid + 1];
        int s = a + c1;
        for (int off = 1; off < 64; off <<= 1) {
            int t = __shfl_up(s, off, 64);
            if (tid >= off) s += t;
        }
        rowoff[2 * tid + 1] = s - c1;        // excl(2t+1)
        rowoff[2 * tid]     = s - c1 - a;    // excl(2t)
    }
    __syncthreads();
    if (tid < 128) {
        int excl = rowoff[tid];
        int node = b * 128 + tid;
        if (node < N) {
            rowptr[node] = beg + excl;
            rowend[node] = beg + excl + cnt[tid];
            norm[node] = cnt[tid] ? rsqrtf((float)cnt[tid]) : 0.0f;
        }
    }
    __syncthreads();
#pragma unroll
    for (int it = 0; it < 5; ++it)
        if (dd[it] >= 0)
            stage[rowoff[dd[it]] + rk[it]] = (unsigned short)(pk[it] & 0xFFFFu);
    __syncthreads();
    unsigned* du = (unsigned*)(csr + beg);  // beg even, base 4B-aligned
    const unsigned* su = (const unsigned*)stage;
    int mu = m >> 1;
    for (int k = tid; k < mu; k += 1024) du[k] = su[k];
    if ((m & 1) && tid == 0) csr[beg + m - 1] = stage[m - 1];
}

// K3 (register-tiled LDS GEMM, split-h2 store): h = (x@W)*norm, fp16, stored
// as h2a[row][0:32] + h2b[row][32:64] (3.2 MB each — the split makes each
// gather working set fit a 4 MB per-XCD L2). Numerics identical to round 3.
__global__ __launch_bounds__(256)
void k_gemm(const float* __restrict__ x, const float* __restrict__ W,
            const float* __restrict__ norm, __half* __restrict__ h2a,
            __half* __restrict__ h2b) {
    __shared__ float xT[64 * 68];        // xT[k*68 + r] = x[rowbase+r][k]  (17 KB)
    __shared__ float Wl[64 * 64];        // Wl[k*64 + d] = W[k][d]          (16 KB)
    int tid = threadIdx.x;
    int rowbase = blockIdx.x * 64;
    {
        const float4* W4 = (const float4*)W;
        float4* Wl4 = (float4*)Wl;
#pragma unroll
        for (int i = 0; i < 4; ++i)
            Wl4[i * 256 + tid] = W4[i * 256 + tid];
    }
    {
        int rr = tid >> 2;
        int c0 = (tid & 3) * 16;
        int row = rowbase + rr;
        if (row >= N) row = N - 1;       // clamp (stores are guarded)
        const float4* xr = (const float4*)(x + (size_t)row * 64 + c0);
#pragma unroll
        for (int i = 0; i < 4; ++i) {
            float4 v = xr[i];
            int c = c0 + i * 4;
            xT[(c + 0) * 68 + rr] = v.x;
            xT[(c + 1) * 68 + rr] = v.y;
            xT[(c + 2) * 68 + rr] = v.z;
            xT[(c + 3) * 68 + rr] = v.w;
        }
    }
    __syncthreads();
    int tx = tid & 15;                   // col group: cols tx*4 .. +3
    int ty = tid >> 4;                   // row group: rows ty*4 .. +3
    float acc[4][4] = {};
#pragma unroll 8
    for (int k = 0; k < 64; ++k) {
        float4 xv = *(const float4*)&xT[k * 68 + ty * 4];
        float4 wv = *(const float4*)&Wl[k * 64 + tx * 4];
        acc[0][0] = fmaf(xv.x, wv.x, acc[0][0]);
        acc[0][1] = fmaf(xv.x, wv.y, acc[0][1]);
        acc[0][2] = fmaf(xv.x, wv.z, acc[0][2]);
        acc[0][3] = fmaf(xv.x, wv.w, acc[0][3]);
        acc[1][0] = fmaf(xv.y, wv.x, acc[1][0]);
        acc[1][1] = fmaf(xv.y, wv.y, acc[1][1]);
        acc[1][2] = fmaf(xv.y, wv.z, acc[1][2]);
        acc[1][3] = fmaf(xv.y, wv.w, acc[1][3]);
        acc[2][0] = fmaf(xv.z, wv.x, acc[2][0]);
        acc[2][1] = fmaf(xv.z, wv.y, acc[2][1]);
        acc[2][2] = fmaf(xv.z, wv.z, acc[2][2]);
        acc[2][3] = fmaf(xv.z, wv.w, acc[2][3]);
        acc[3][0] = fmaf(xv.w, wv.x, acc[3][0]);
        acc[3][1] = fmaf(xv.w, wv.y, acc[3][1]);
        acc[3][2] = fmaf(xv.w, wv.z, acc[3][2]);
        acc[3][3] = fmaf(xv.w, wv.w, acc[3][3]);
    }
#pragma unroll
    for (int i = 0; i < 4; ++i) {
        int row = rowbase + ty * 4 + i;
        if (row < N) {
            float nr = norm[row];
            __half2 p0 = __floats2half2_rn(acc[i][0] * nr, acc[i][1] * nr);
            __half2 p1 = __floats2half2_rn(acc[i][2] * nr, acc[i][3] * nr);
            __half2* d2;
            if (tx < 8) d2 = (__half2*)(h2a + (size_t)row * 32 + tx * 4);
            else        d2 = (__half2*)(h2b + (size_t)row * 32 + (tx - 8) * 4);
            d2[0] = p0;
            d2[1] = p1;
        }
    }
}

// K4 (half-feature aggregate pass): one wave per node, gathers 64B/edge from
// a 3.2 MB array that fits per-XCD L2 (the lever: round-5 counters showed
// 48 MB HBM fetch for a 6.4 MB h2 -> L2 capacity miss). 4 edges per
// wave-instr (quarter q = lane>>4, feature-pair fp = lane&15). Two passes
// launched sequentially so each pass's working set stays resident. csr loads
// and out stores nontemporal (scalar floats — the builtin rejects float2)
// to keep L2 for h2.
__global__ void k_agg_half(const int* __restrict__ rowptr, const int* __restrict__ rowend,
                           const unsigned short* __restrict__ csr,
                           const __half* __restrict__ h2h, const float* __restrict__ norm,
                           const float* __restrict__ bias, float* __restrict__ out,
                           int foff) {
    int node = blockIdx.x * 4 + (threadIdx.x >> 6);
    int lane = threadIdx.x & 63;
    int q  = lane >> 4;            // which edge of the quad
    int fp = lane & 15;            // feature-pair index (features 2fp, 2fp+1 of this half)
    const __half2* hv = (const __half2*)h2h;   // row stride 16 (64B rows)
    int beg = rowptr[node];
    int end = rowend[node];
    int deg = end - beg;
    int myidx = (beg + lane < end) ? (int)__builtin_nontemporal_load(&csr[beg + lane]) : 0;
    int window = deg < 64 ? deg : 64;   // wave-uniform
    int ngrp = window >> 2;             // quads of edges
    float a0x = 0.0f, a0y = 0.0f, a1x = 0.0f, a1y = 0.0f;
    int g = 0;
    for (; g + 3 < ngrp; g += 4) {      // 16 edges per iteration, 4 loads in flight
        int s0 = __shfl(myidx, 4 * g + q, 64);
        int s1 = __shfl(myidx, 4 * g + 4 + q, 64);
        int s2 = __shfl(myidx, 4 * g + 8 + q, 64);
        int s3 = __shfl(myidx, 4 * g + 12 + q, 64);
        float2 v0 = __half22float2(hv[s0 * 16 + fp]);
        float2 v1 = __half22float2(hv[s1 * 16 + fp]);
        float2 v2 = __half22float2(hv[s2 * 16 + fp]);
        float2 v3 = __half22float2(hv[s3 * 16 + fp]);
        a0x += v0.x + v2.x;  a0y += v0.y + v2.y;
        a1x += v1.x + v3.x;  a1y += v1.y + v3.y;
    }
    for (; g < ngrp; ++g) {             // quad tail (uniform trip count)
        int s = __shfl(myidx, 4 * g + q, 64);
        float2 v = __half22float2(hv[s * 16 + fp]);
        a0x += v.x;  a0y += v.y;
    }
    int rem = window & 3;
    if (rem) {                          // wave-uniform: all lanes shfl
        int s = __shfl(myidx, (window & ~3) + (q < rem ? q : 0), 64);
        if (q < rem) {
            float2 v = __half22float2(hv[s * 16 + fp]);
            a0x += v.x;  a0y += v.y;
        }
    }
    if (deg > 64) {                     // rare fallback, direct loads
        int j = beg + 64;
        for (; j + 3 < end; j += 4) {
            int s = __builtin_nontemporal_load(&csr[j + q]);
            float2 v = __half22float2(hv[s * 16 + fp]);
            a0x += v.x;  a0y += v.y;
        }
        int r2 = end - j;
        if (r2 > 0 && q < r2) {
            int s = __builtin_nontemporal_load(&csr[j + q]);
            float2 v = __half22float2(hv[s * 16 + fp]);
            a0x += v.x;  a0y += v.y;
        }
    }
    float ax = a0x + a1x, ay = a0y + a1y;
    ax += __shfl_xor(ax, 16, 64);       // combine the 4 quarter-lanes
    ay += __shfl_xor(ay, 16, 64);
    ax += __shfl_xor(ax, 32, 64);
    ay += __shfl_xor(ay, 32, 64);
    if (q == 0) {
        float nrm = norm[node];
        float2 bs = ((const float2*)(bias + foff))[fp];
        float vx = ax * nrm + bs.x;
        float vy = ay * nrm + bs.y;
        float ox = fmaxf(vx, 0.0f) + log1pf(expf(-fabsf(vx)));
        float oy = fmaxf(vy, 0.0f) + log1pf(expf(-fabsf(vy)));
        float* op = out + (size_t)node * 64 + foff + 2 * fp;
        __builtin_nontemporal_store(ox, op);
        __builtin_nontemporal_store(oy, op + 1);
    }
}

extern "C" void kernel_launch(void* const* d_in, const int* in_sizes, int n_in,
                              void* d_out, int out_size, void* d_ws, size_t ws_size,
                              hipStream_t stream) {
    // inputs: t(f32,1), x(f32,N*D), weight(f32,D*D), bias(f32,D), src(i32,E), dst(i32,E)
    const float* x    = (const float*)d_in[1];
    const float* W    = (const float*)d_in[2];
    const float* bias = (const float*)d_in[3];
    const int* src = (const int*)d_in[4];
    const int* dst = (const int*)d_in[5];
    float* out = (float*)d_out;

    // workspace layout (~17.9 MB; poisoned every call — every buffer is
    // fully written before it is read)
    char* ws = (char*)d_ws;
    __half*         h2a    = (__half*)(ws);                     // N*32*2 = 3.2 MB
    __half*         h2b    = (__half*)(ws + 3200000);           // N*32*2 = 3.2 MB
    unsigned*       packed = (unsigned*)(ws + 6400000);         // NBUCK*CAP*4 = 7.21 MB
    unsigned short* csr    = (unsigned short*)(ws + 13606912);  // NBUCK*CAP*2 = 3.6 MB
    int*            rowptr = (int*)(ws + 17210368);             // N*4
    int*            rowend = (int*)(ws + 17410368);             // N*4
    float*          norm   = (float*)(ws + 17610368);           // N*4
    int*            cursor = (int*)(ws + 17810368);             // NBUCK*4

    k_init    <<<1, 512, 0, stream>>>(cursor);
    k_bucket  <<<BBLOCKS, BTHREADS, 0, stream>>>(src, dst, cursor, packed);
    k_csr     <<<NBUCK, 1024, 0, stream>>>(cursor, packed, csr, rowptr, rowend, norm);
    k_gemm    <<<(N + 63) / 64, 256, 0, stream>>>(x, W, norm, h2a, h2b);
    k_agg_half<<<(N + 3) / 4, 256, 0, stream>>>(rowptr, rowend, csr, h2a, norm, bias, out, 0);
    k_agg_half<<<(N + 3) / 4, 256, 0, stream>>>(rowptr, rowend, csr, h2b, norm, bias, out, 32);
}

// Round 11
// 155.555 us; speedup vs baseline: 1.0994x; 1.0994x over previous
//
#include <hip/hip_runtime.h>
#include <hip/hip_fp16.h>

constexpr int N = 50000;        // nodes
constexpr int D = 64;           // feature dim
constexpr int E = 1600000;      // edges
constexpr int NBUCK = (N + 127) / 128;   // 391 buckets of 128 nodes (dst>>7)
constexpr int CAP = 4608;                // bucket window capacity (mean 4092)
constexpr int BTHREADS = 1024;
constexpr int BBLOCKS = 256;             // verified round-7 config
constexpr int EPB = E / BBLOCKS;         // 6250 edges per block (exact)
constexpr int CPT = (EPB + BTHREADS - 1) / BTHREADS;  // 7
constexpr int SPLIT = 25000;             // src-range split: each half of h2 = 3.2 MB <= 4 MB L2/XCD

// ---------------------------------------------------------------------------
// K0: init per-bucket window cursors (cursor[b] = b*CAP)
__global__ void k_init(int* __restrict__ cursor) {
    int t = threadIdx.x;
    if (t < NBUCK) cursor[t] = t * CAP;
}

// K1: privatized counting-sort scatter -> fixed-capacity bucket windows.
// packed = dst<<16 | src (both < 65536); bucket = packed>>23.
// (verified round-7 version, unchanged)
__global__ __launch_bounds__(1024)
void k_bucket(const int* __restrict__ src, const int* __restrict__ dst,
              int* __restrict__ cursor, unsigned* __restrict__ packed) {
    __shared__ int lh[NBUCK];
    __shared__ int scanI[NBUCK];         // inclusive prefix over buckets
    __shared__ int wsum[16];             // 16 waves
    __shared__ int lb[NBUCK];
    __shared__ unsigned stage[EPB];      // 25 KB
    int tid = threadIdx.x;
    if (tid < NBUCK) lh[tid] = 0;
    __syncthreads();
    int base_e = blockIdx.x * EPB;
    unsigned pk[CPT];
    int bn[CPT], rk[CPT];
#pragma unroll
    for (int i = 0; i < CPT; ++i) {
        int idx = i * BTHREADS + tid;
        if (idx < EPB) {
            int e = base_e + idx;
            int d = dst[e];
            int s = src[e];
            bn[i] = d >> 7;
            pk[i] = ((unsigned)d << 16) | (unsigned)s;
            rk[i] = atomicAdd(&lh[bn[i]], 1);
        } else bn[i] = -1;
    }
    __syncthreads();
    // hierarchical inclusive scan of lh[0..NBUCK) into scanI
    int w = tid >> 6, l = tid & 63;
    int v = (tid < NBUCK) ? lh[tid] : 0;
    for (int off = 1; off < 64; off <<= 1) {
        int t = __shfl_up(v, off, 64);
        if (l >= off) v += t;
    }
    if (tid < NBUCK) scanI[tid] = v;
    if (l == 63) wsum[w] = v;
    __syncthreads();
    if (tid < 64) {                      // wave 0 scans the 16 wave sums
        int s = (tid < 16) ? wsum[tid] : 0;
        for (int off = 1; off < 16; off <<= 1) {
            int t = __shfl_up(s, off, 64);
            if (tid >= off) s += t;
        }
        if (tid < 16) wsum[tid] = s;
    }
    __syncthreads();
    if (tid < NBUCK && w > 0) scanI[tid] += wsum[w - 1];
    if (tid < NBUCK) {
        int c = lh[tid];
        lb[tid] = c ? atomicAdd(&cursor[tid], c) : 0;   // one global atomic/bucket/block
    }
    __syncthreads();
#pragma unroll
    for (int i = 0; i < CPT; ++i) {
        if (bn[i] >= 0) {
            int eb = (bn[i] == 0) ? 0 : scanI[bn[i] - 1];
            stage[eb + rk[i]] = pk[i];   // LDS scatter into bucket-sorted order
        }
    }
    __syncthreads();
    for (int j = tid; j < EPB; j += BTHREADS) {
        unsigned vv = stage[j];
        int bk = vv >> 23;               // dst>>7
        int eb = (bk == 0) ? 0 : scanI[bk - 1];
        packed[lb[bk] + (j - eb)] = vv;  // contiguous within each chunk
    }
}

// K2 (single-pass CSR, 256 bins): bin = local_node*2 + (src>=SPLIT).
// Within each node the edge list is partitioned [src<SPLIT | src>=SPLIT] so
// the aggregate can run as two L2-resident passes. Rank from the histogram
// atomicAdd IS the stable slot (round-7 verified mechanism).
__global__ __launch_bounds__(1024)
void k_csr(const int* __restrict__ cursor, const unsigned* __restrict__ packed,
           unsigned short* __restrict__ csr, int* __restrict__ rowptr,
           int* __restrict__ rowmid, int* __restrict__ rowend,
           float* __restrict__ norm) {
    __shared__ int cnt[256];
    __shared__ int rowoff[256];          // exclusive prefix over 256 bins
    __shared__ unsigned short stage[CAP];   // 9 KB node-sorted src list
    int b = blockIdx.x, tid = threadIdx.x;
    if (tid < 256) cnt[tid] = 0;
    __syncthreads();
    int beg = b * CAP;
    int m = cursor[b] - beg;             // edges in this bucket (<= CAP)
    unsigned pk[5];
    int rk[5], bb[5];
#pragma unroll
    for (int it = 0; it < 5; ++it) {     // ceil(CAP/1024) = 5
        int j = it * 1024 + tid;
        if (j < m) {
            unsigned p = packed[beg + j];
            int bin = (((p >> 16) & 127) << 1) | ((p & 0xFFFFu) >= (unsigned)SPLIT ? 1 : 0);
            bb[it] = bin;
            pk[it] = p;
            rk[it] = atomicAdd(&cnt[bin], 1);   // rank = stable slot
        } else bb[it] = -1;
    }
    __syncthreads();
    if (tid < 64) {                      // wave 0: 4 bins/lane inclusive scan
        int c0 = cnt[4 * tid], c1 = cnt[4 * tid + 1];
        int c2 = cnt[4 * tid + 2], c3 = cnt[4 * tid + 3];
        int s = c0 + c1 + c2 + c3;
        for (int off = 1; off < 64; off <<= 1) {
            int t = __shfl_up(s, off, 64);
            if (tid >= off) s += t;
        }
        int base = s - (c0 + c1 + c2 + c3);  // exclusive base of this lane's group
        rowoff[4 * tid]     = base;
        rowoff[4 * tid + 1] = base + c0;
        rowoff[4 * tid + 2] = base + c0 + c1;
        rowoff[4 * tid + 3] = base + c0 + c1 + c2;
    }
    __syncthreads();
    if (tid < 128) {
        int node = b * 128 + tid;
        if (node < N) {
            int ca = cnt[2 * tid], cb = cnt[2 * tid + 1];
            rowptr[node] = beg + rowoff[2 * tid];
            rowmid[node] = beg + rowoff[2 * tid + 1];
            rowend[node] = beg + rowoff[2 * tid + 1] + cb;
            int dg = ca + cb;
            norm[node] = dg ? rsqrtf((float)dg) : 0.0f;
        }
    }
    __syncthreads();
#pragma unroll
    for (int it = 0; it < 5; ++it)
        if (bb[it] >= 0)
            stage[rowoff[bb[it]] + rk[it]] = (unsigned short)(pk[it] & 0xFFFFu);
    __syncthreads();
    unsigned* du = (unsigned*)(csr + beg);  // beg even, base 4B-aligned
    const unsigned* su = (const unsigned*)stage;
    int mu = m >> 1;
    for (int k = tid; k < mu; k += 1024) du[k] = su[k];
    if ((m & 1) && tid == 0) csr[beg + m - 1] = stage[m - 1];
}

// K3 (register-tiled LDS GEMM): h2[row][d] = (x@W)[row][d] * norm[row], fp16.
// (verified round-3 version, unchanged — single 6.4 MB h2, 128B rows)
__global__ __launch_bounds__(256)
void k_gemm(const float* __restrict__ x, const float* __restrict__ W,
            const float* __restrict__ norm, __half* __restrict__ h2) {
    __shared__ float xT[64 * 68];        // xT[k*68 + r] = x[rowbase+r][k]  (17 KB)
    __shared__ float Wl[64 * 64];        // Wl[k*64 + d] = W[k][d]          (16 KB)
    int tid = threadIdx.x;
    int rowbase = blockIdx.x * 64;
    {
        const float4* W4 = (const float4*)W;
        float4* Wl4 = (float4*)Wl;
#pragma unroll
        for (int i = 0; i < 4; ++i)
            Wl4[i * 256 + tid] = W4[i * 256 + tid];
    }
    {
        int rr = tid >> 2;
        int c0 = (tid & 3) * 16;
        int row = rowbase + rr;
        if (row >= N) row = N - 1;       // clamp (stores are guarded)
        const float4* xr = (const float4*)(x + (size_t)row * 64 + c0);
#pragma unroll
        for (int i = 0; i < 4; ++i) {
            float4 v = xr[i];
            int c = c0 + i * 4;
            xT[(c + 0) * 68 + rr] = v.x;
            xT[(c + 1) * 68 + rr] = v.y;
            xT[(c + 2) * 68 + rr] = v.z;
            xT[(c + 3) * 68 + rr] = v.w;
        }
    }
    __syncthreads();
    int tx = tid & 15;                   // col group: cols tx*4 .. +3
    int ty = tid >> 4;                   // row group: rows ty*4 .. +3
    float acc[4][4] = {};
#pragma unroll 8
    for (int k = 0; k < 64; ++k) {
        float4 xv = *(const float4*)&xT[k * 68 + ty * 4];
        float4 wv = *(const float4*)&Wl[k * 64 + tx * 4];
        acc[0][0] = fmaf(xv.x, wv.x, acc[0][0]);
        acc[0][1] = fmaf(xv.x, wv.y, acc[0][1]);
        acc[0][2] = fmaf(xv.x, wv.z, acc[0][2]);
        acc[0][3] = fmaf(xv.x, wv.w, acc[0][3]);
        acc[1][0] = fmaf(xv.y, wv.x, acc[1][0]);
        acc[1][1] = fmaf(xv.y, wv.y, acc[1][1]);
        acc[1][2] = fmaf(xv.y, wv.z, acc[1][2]);
        acc[1][3] = fmaf(xv.y, wv.w, acc[1][3]);
        acc[2][0] = fmaf(xv.z, wv.x, acc[2][0]);
        acc[2][1] = fmaf(xv.z, wv.y, acc[2][1]);
        acc[2][2] = fmaf(xv.z, wv.z, acc[2][2]);
        acc[2][3] = fmaf(xv.z, wv.w, acc[2][3]);
        acc[3][0] = fmaf(xv.w, wv.x, acc[3][0]);
        acc[3][1] = fmaf(xv.w, wv.y, acc[3][1]);
        acc[3][2] = fmaf(xv.w, wv.z, acc[3][2]);
        acc[3][3] = fmaf(xv.w, wv.w, acc[3][3]);
    }
#pragma unroll
    for (int i = 0; i < 4; ++i) {
        int row = rowbase + ty * 4 + i;
        if (row < N) {
            float nr = norm[row];
            __half2 p0 = __floats2half2_rn(acc[i][0] * nr, acc[i][1] * nr);
            __half2 p1 = __floats2half2_rn(acc[i][2] * nr, acc[i][3] * nr);
            __half2* dst2 = (__half2*)(h2 + (size_t)row * 64 + tx * 4);
            dst2[0] = p0;
            dst2[1] = p1;
        }
    }
}

// K4 (src-range aggregate pass): round-7 verified gather structure (wave per
// node, 2 edges / 128B-row instr, 8 loads in flight), but over the [lo,hi)
// sub-list only. Pass A (FINAL=false) gathers src<SPLIT (h2 rows 0..25K =
// 3.2 MB, fits per-XCD L2) and writes raw fp32 partial sums to out. Pass B
// (FINAL=true) gathers src>=SPLIT, adds the partials, applies dst-norm +
// bias + softplus. Same per-edge instruction AND transaction count as the
// single-pass version — only the cache working set halves (round-10's
// feature-split failure mode was doubled transactions; this avoids it).
template<bool FINAL>
__global__ void k_agg_pass(const int* __restrict__ lo, const int* __restrict__ hi,
                           const unsigned short* __restrict__ csr,
                           const __half* __restrict__ h2, const float* __restrict__ norm,
                           const float* __restrict__ bias, float* __restrict__ out) {
    int node = blockIdx.x * 4 + (threadIdx.x >> 6);
    int lane = threadIdx.x & 63;
    int half = lane >> 5;          // which edge of the pair
    int fl = lane & 31;            // feature-pair index (features 2fl, 2fl+1)
    const __half2* h2v = (const __half2*)h2;   // row stride 32
    int beg = lo[node];
    int end = hi[node];
    int deg = end - beg;
    int myidx = (beg + lane < end) ? (int)csr[beg + lane] : 0;
    int window = deg < 64 ? deg : 64;   // wave-uniform
    int npair = window >> 1;
    float ax = 0.0f, ay = 0.0f, bx = 0.0f, by = 0.0f;
    int p = 0;
    for (; p + 7 < npair; p += 8) {          // 16 edges per iteration, 8 loads in flight
        int s0 = __shfl(myidx, 2 * p + half, 64);
        int s1 = __shfl(myidx, 2 * p + 2 + half, 64);
        int s2 = __shfl(myidx, 2 * p + 4 + half, 64);
        int s3 = __shfl(myidx, 2 * p + 6 + half, 64);
        int s4 = __shfl(myidx, 2 * p + 8 + half, 64);
        int s5 = __shfl(myidx, 2 * p + 10 + half, 64);
        int s6 = __shfl(myidx, 2 * p + 12 + half, 64);
        int s7 = __shfl(myidx, 2 * p + 14 + half, 64);
        float2 v0 = __half22float2(h2v[s0 * 32 + fl]);
        float2 v1 = __half22float2(h2v[s1 * 32 + fl]);
        float2 v2 = __half22float2(h2v[s2 * 32 + fl]);
        float2 v3 = __half22float2(h2v[s3 * 32 + fl]);
        float2 v4 = __half22float2(h2v[s4 * 32 + fl]);
        float2 v5 = __half22float2(h2v[s5 * 32 + fl]);
        float2 v6 = __half22float2(h2v[s6 * 32 + fl]);
        float2 v7 = __half22float2(h2v[s7 * 32 + fl]);
        ax += (v0.x + v2.x) + (v4.x + v6.x);
        ay += (v0.y + v2.y) + (v4.y + v6.y);
        bx += (v1.x + v3.x) + (v5.x + v7.x);
        by += (v1.y + v3.y) + (v5.y + v7.y);
    }
    for (; p + 3 < npair; p += 4) {          // 8 edges per iteration
        int s0 = __shfl(myidx, 2 * p + half, 64);
        int s1 = __shfl(myidx, 2 * p + 2 + half, 64);
        int s2 = __shfl(myidx, 2 * p + 4 + half, 64);
        int s3 = __shfl(myidx, 2 * p + 6 + half, 64);
        float2 v0 = __half22float2(h2v[s0 * 32 + fl]);
        float2 v1 = __half22float2(h2v[s1 * 32 + fl]);
        float2 v2 = __half22float2(h2v[s2 * 32 + fl]);
        float2 v3 = __half22float2(h2v[s3 * 32 + fl]);
        ax += v0.x + v2.x;  ay += v0.y + v2.y;
        bx += v1.x + v3.x;  by += v1.y + v3.y;
    }
    for (; p < npair; ++p) {                 // pair tail (uniform trip count)
        int s = __shfl(myidx, 2 * p + half, 64);
        float2 v = __half22float2(h2v[s * 32 + fl]);
        ax += v.x;  ay += v.y;
    }
    if (window & 1) {                        // wave-uniform: all lanes shfl
        int s = __shfl(myidx, window - 1, 64);
        float2 v = __half22float2(h2v[s * 32 + fl]);
        if (half == 0) { ax += v.x;  ay += v.y; }
    }
    if (deg > 64) {                          // rare fallback, direct loads
        int j = beg + 64;
        for (; j + 1 < end; j += 2) {
            int s = csr[j + half];
            float2 v = __half22float2(h2v[s * 32 + fl]);
            ax += v.x;  ay += v.y;
        }
        if (j < end) {
            int s = csr[j];
            float2 v = __half22float2(h2v[s * 32 + fl]);
            if (half == 0) { ax += v.x;  ay += v.y; }
        }
    }
    ax += bx;  ay += by;
    ax += __shfl_xor(ax, 32, 64);            // combine the two half-waves
    ay += __shfl_xor(ay, 32, 64);
    if (half == 0) {
        float2* op = (float2*)out + (size_t)node * 32 + fl;
        if (FINAL) {
            float2 prev = *op;               // partial sums from pass A
            float nrm = norm[node];
            float2 bs = ((const float2*)bias)[fl];
            float vx = (ax + prev.x) * nrm + bs.x;
            float vy = (ay + prev.y) * nrm + bs.y;
            float2 o;
            o.x = fmaxf(vx, 0.0f) + log1pf(expf(-fabsf(vx)));
            o.y = fmaxf(vy, 0.0f) + log1pf(expf(-fabsf(vy)));
            *op = o;
        } else {
            *op = make_float2(ax, ay);       // raw partial (out reused as scratch)
        }
    }
}

extern "C" void kernel_launch(void* const* d_in, const int* in_sizes, int n_in,
                              void* d_out, int out_size, void* d_ws, size_t ws_size,
                              hipStream_t stream) {
    // inputs: t(f32,1), x(f32,N*D), weight(f32,D*D), bias(f32,D), src(i32,E), dst(i32,E)
    const float* x    = (const float*)d_in[1];
    const float* W    = (const float*)d_in[2];
    const float* bias = (const float*)d_in[3];
    const int* src = (const int*)d_in[4];
    const int* dst = (const int*)d_in[5];
    float* out = (float*)d_out;

    // workspace layout (~18.0 MB; poisoned every call — every buffer is
    // fully written before it is read)
    char* ws = (char*)d_ws;
    __half*         h2     = (__half*)(ws);                     // 6.4 MB
    unsigned*       packed = (unsigned*)(ws + 6400000);         // NBUCK*CAP*4 = 7.21 MB
    unsigned short* csr    = (unsigned short*)(ws + 13606912);  // NBUCK*CAP*2 = 3.6 MB
    int*            rowptr = (int*)(ws + 17210368);             // N*4
    int*            rowmid = (int*)(ws + 17410368);             // N*4
    int*            rowend = (int*)(ws + 17610368);             // N*4
    float*          norm   = (float*)(ws + 17810368);           // N*4
    int*            cursor = (int*)(ws + 18010368);             // NBUCK*4

    k_init   <<<1, 512, 0, stream>>>(cursor);
    k_bucket <<<BBLOCKS, BTHREADS, 0, stream>>>(src, dst, cursor, packed);
    k_csr    <<<NBUCK, 1024, 0, stream>>>(cursor, packed, csr, rowptr, rowmid, rowend, norm);
    k_gemm   <<<(N + 63) / 64, 256, 0, stream>>>(x, W, norm, h2);
    k_agg_pass<false><<<(N + 3) / 4, 256, 0, stream>>>(rowptr, rowmid, csr, h2, norm, bias, out);
    k_agg_pass<true> <<<(N + 3) / 4, 256, 0, stream>>>(rowmid, rowend, csr, h2, norm, bias, out);
}

// Round 12
// 143.147 us; speedup vs baseline: 1.1946x; 1.0867x over previous
//
#include <hip/hip_runtime.h>
#include <hip/hip_fp16.h>

constexpr int N = 50000;        // nodes
constexpr int D = 64;           // feature dim
constexpr int E = 1600000;      // edges
constexpr int NBUCK = (N + 127) / 128;   // 391 buckets of 128 nodes (dst>>7)
constexpr int CAP = 4608;                // bucket window capacity (mean 4092)
constexpr int BTHREADS = 1024;
constexpr int BBLOCKS = 128;             // was 256: halves cursor-atomic queue depth
                                         // per address; copy-out chunks -> ~32 edges (128B)
constexpr int EPB = E / BBLOCKS;         // 12500 edges per block (exact)
constexpr int CPT = (EPB + BTHREADS - 1) / BTHREADS;  // 13

// ---------------------------------------------------------------------------
// K0: init per-bucket window cursors (cursor[b] = b*CAP)
__global__ void k_init(int* __restrict__ cursor) {
    int t = threadIdx.x;
    if (t < NBUCK) cursor[t] = t * CAP;
}

// K1: privatized counting-sort scatter -> fixed-capacity bucket windows.
// packed = dst<<16 | src (both < 65536); bucket = packed>>23.
// Round-12 changes vs verified round-7 version:
//  (a) 128 blocks x EPB=12500 (stage 50 KB) — halves the 391-address global
//      cursor-atomic contention tail (each addr now serializes 128 returns,
//      not 256) and doubles copy-out chunk length.
//  (b) cursor atomicAdd issued RIGHT AFTER the histogram sync with the result
//      held in a register; lb[] written only after the LDS scatter — the
//      atomic's queue latency overlaps the whole scan+scatter phase instead
//      of sitting on the critical path.
__global__ __launch_bounds__(1024)
void k_bucket(const int* __restrict__ src, const int* __restrict__ dst,
              int* __restrict__ cursor, unsigned* __restrict__ packed) {
    __shared__ int lh[NBUCK];
    __shared__ int scanI[NBUCK];         // inclusive prefix over buckets
    __shared__ int wsum[16];             // 16 waves
    __shared__ int lb[NBUCK];
    __shared__ unsigned stage[EPB];      // 50 KB
    int tid = threadIdx.x;
    if (tid < NBUCK) lh[tid] = 0;
    __syncthreads();
    int base_e = blockIdx.x * EPB;
    unsigned pk[CPT];
    int bn[CPT], rk[CPT];
#pragma unroll
    for (int i = 0; i < CPT; ++i) {
        int idx = i * BTHREADS + tid;
        if (idx < EPB) {
            int e = base_e + idx;
            int d = dst[e];
            int s = src[e];
            bn[i] = d >> 7;
            pk[i] = ((unsigned)d << 16) | (unsigned)s;
            rk[i] = atomicAdd(&lh[bn[i]], 1);
        } else bn[i] = -1;
    }
    __syncthreads();
    // (b) issue the global cursor atomic NOW; result parked in a register
    int myLb = 0;
    if (tid < NBUCK) {
        int c = lh[tid];
        if (c) myLb = atomicAdd(&cursor[tid], c);
    }
    // hierarchical inclusive scan of lh[0..NBUCK) into scanI
    int w = tid >> 6, l = tid & 63;
    int v = (tid < NBUCK) ? lh[tid] : 0;
    for (int off = 1; off < 64; off <<= 1) {
        int t = __shfl_up(v, off, 64);
        if (l >= off) v += t;
    }
    if (tid < NBUCK) scanI[tid] = v;
    if (l == 63) wsum[w] = v;
    __syncthreads();
    if (tid < 64) {                      // wave 0 scans the 16 wave sums
        int s = (tid < 16) ? wsum[tid] : 0;
        for (int off = 1; off < 16; off <<= 1) {
            int t = __shfl_up(s, off, 64);
            if (tid >= off) s += t;
        }
        if (tid < 16) wsum[tid] = s;
    }
    __syncthreads();
    if (tid < NBUCK && w > 0) scanI[tid] += wsum[w - 1];
    __syncthreads();
#pragma unroll
    for (int i = 0; i < CPT; ++i) {
        if (bn[i] >= 0) {
            int eb = (bn[i] == 0) ? 0 : scanI[bn[i] - 1];
            stage[eb + rk[i]] = pk[i];   // LDS scatter into bucket-sorted order
        }
    }
    if (tid < NBUCK) lb[tid] = myLb;     // atomic result lands here (post-scatter)
    __syncthreads();
    for (int j = tid; j < EPB; j += BTHREADS) {
        unsigned vv = stage[j];
        int bk = vv >> 23;               // dst>>7
        int eb = (bk == 0) ? 0 : scanI[bk - 1];
        packed[lb[bk] + (j - eb)] = vv;  // contiguous within each chunk
    }
}

// K2 (single-pass CSR): rank from the histogram atomicAdd IS the stable slot.
// (verified round-7 version, unchanged)
__global__ __launch_bounds__(1024)
void k_csr(const int* __restrict__ cursor, const unsigned* __restrict__ packed,
           unsigned short* __restrict__ csr, int* __restrict__ rowptr,
           int* __restrict__ rowend, float* __restrict__ norm) {
    __shared__ int cnt[128];
    __shared__ int rowoff[128];          // exclusive prefix over 128 bins
    __shared__ unsigned short stage[CAP];   // 9 KB node-sorted src list
    int b = blockIdx.x, tid = threadIdx.x;
    if (tid < 128) cnt[tid] = 0;
    __syncthreads();
    int beg = b * CAP;
    int m = cursor[b] - beg;             // edges in this bucket (<= CAP)
    unsigned pk[5];
    int rk[5], dd[5];
#pragma unroll
    for (int it = 0; it < 5; ++it) {     // ceil(CAP/1024) = 5
        int j = it * 1024 + tid;
        if (j < m) {
            unsigned p = packed[beg + j];
            int d = (p >> 16) & 127;
            dd[it] = d;
            pk[it] = p;
            rk[it] = atomicAdd(&cnt[d], 1);   // rank = stable slot
        } else dd[it] = -1;
    }
    __syncthreads();
    if (tid < 64) {                      // wave 0: 2 bins/lane inclusive scan
        int a = cnt[2 * tid], c1 = cnt[2 * tid + 1];
        int s = a + c1;
        for (int off = 1; off < 64; off <<= 1) {
            int t = __shfl_up(s, off, 64);
            if (tid >= off) s += t;
        }
        rowoff[2 * tid + 1] = s - c1;        // excl(2t+1)
        rowoff[2 * tid]     = s - c1 - a;    // excl(2t)
    }
    __syncthreads();
    if (tid < 128) {
        int excl = rowoff[tid];
        int node = b * 128 + tid;
        if (node < N) {
            rowptr[node] = beg + excl;
            rowend[node] = beg + excl + cnt[tid];
            norm[node] = cnt[tid] ? rsqrtf((float)cnt[tid]) : 0.0f;
        }
    }
    __syncthreads();
#pragma unroll
    for (int it = 0; it < 5; ++it)
        if (dd[it] >= 0)
            stage[rowoff[dd[it]] + rk[it]] = (unsigned short)(pk[it] & 0xFFFFu);
    __syncthreads();
    unsigned* du = (unsigned*)(csr + beg);  // beg even, base 4B-aligned
    const unsigned* su = (const unsigned*)stage;
    int mu = m >> 1;
    for (int k = tid; k < mu; k += 1024) du[k] = su[k];
    if ((m & 1) && tid == 0) csr[beg + m - 1] = stage[m - 1];
}

// K3 (register-tiled LDS GEMM): h2[row][d] = (x@W)[row][d] * norm[row], fp16.
// (verified round-3 version, unchanged)
__global__ __launch_bounds__(256)
void k_gemm(const float* __restrict__ x, const float* __restrict__ W,
            const float* __restrict__ norm, __half* __restrict__ h2) {
    __shared__ float xT[64 * 68];        // xT[k*68 + r] = x[rowbase+r][k]  (17 KB)
    __shared__ float Wl[64 * 64];        // Wl[k*64 + d] = W[k][d]          (16 KB)
    int tid = threadIdx.x;
    int rowbase = blockIdx.x * 64;
    {
        const float4* W4 = (const float4*)W;
        float4* Wl4 = (float4*)Wl;
#pragma unroll
        for (int i = 0; i < 4; ++i)
            Wl4[i * 256 + tid] = W4[i * 256 + tid];
    }
    {
        int rr = tid >> 2;
        int c0 = (tid & 3) * 16;
        int row = rowbase + rr;
        if (row >= N) row = N - 1;       // clamp (stores are guarded)
        const float4* xr = (const float4*)(x + (size_t)row * 64 + c0);
#pragma unroll
        for (int i = 0; i < 4; ++i) {
            float4 v = xr[i];
            int c = c0 + i * 4;
            xT[(c + 0) * 68 + rr] = v.x;
            xT[(c + 1) * 68 + rr] = v.y;
            xT[(c + 2) * 68 + rr] = v.z;
            xT[(c + 3) * 68 + rr] = v.w;
        }
    }
    __syncthreads();
    int tx = tid & 15;                   // col group: cols tx*4 .. +3
    int ty = tid >> 4;                   // row group: rows ty*4 .. +3
    float acc[4][4] = {};
#pragma unroll 8
    for (int k = 0; k < 64; ++k) {
        float4 xv = *(const float4*)&xT[k * 68 + ty * 4];
        float4 wv = *(const float4*)&Wl[k * 64 + tx * 4];
        acc[0][0] = fmaf(xv.x, wv.x, acc[0][0]);
        acc[0][1] = fmaf(xv.x, wv.y, acc[0][1]);
        acc[0][2] = fmaf(xv.x, wv.z, acc[0][2]);
        acc[0][3] = fmaf(xv.x, wv.w, acc[0][3]);
        acc[1][0] = fmaf(xv.y, wv.x, acc[1][0]);
        acc[1][1] = fmaf(xv.y, wv.y, acc[1][1]);
        acc[1][2] = fmaf(xv.y, wv.z, acc[1][2]);
        acc[1][3] = fmaf(xv.y, wv.w, acc[1][3]);
        acc[2][0] = fmaf(xv.z, wv.x, acc[2][0]);
        acc[2][1] = fmaf(xv.z, wv.y, acc[2][1]);
        acc[2][2] = fmaf(xv.z, wv.z, acc[2][2]);
        acc[2][3] = fmaf(xv.z, wv.w, acc[2][3]);
        acc[3][0] = fmaf(xv.w, wv.x, acc[3][0]);
        acc[3][1] = fmaf(xv.w, wv.y, acc[3][1]);
        acc[3][2] = fmaf(xv.w, wv.z, acc[3][2]);
        acc[3][3] = fmaf(xv.w, wv.w, acc[3][3]);
    }
#pragma unroll
    for (int i = 0; i < 4; ++i) {
        int row = rowbase + ty * 4 + i;
        if (row < N) {
            float nr = norm[row];
            __half2 p0 = __floats2half2_rn(acc[i][0] * nr, acc[i][1] * nr);
            __half2 p1 = __floats2half2_rn(acc[i][2] * nr, acc[i][3] * nr);
            __half2* dst2 = (__half2*)(h2 + (size_t)row * 64 + tx * 4);
            dst2[0] = p0;
            dst2[1] = p1;
        }
    }
}

// K4: fused aggregate + dst-norm + bias + softplus.
// One wave per node (12500 blocks x 4 waves = 50K waves of TLP — round-5/11
// proved fewer-waves or split-list shapes are slower). (verified round-3
// version, unchanged; ~29 µs = 7.1 TB/s effective gather, at practical floor)
__global__ void k_aggregate(const int* __restrict__ rowptr, const int* __restrict__ rowend,
                            const unsigned short* __restrict__ csr,
                            const __half* __restrict__ h2, const float* __restrict__ norm,
                            const float* __restrict__ bias, float* __restrict__ out) {
    int node = blockIdx.x * 4 + (threadIdx.x >> 6);
    int lane = threadIdx.x & 63;
    int half = lane >> 5;          // which edge of the pair
    int fl = lane & 31;            // feature-pair index (features 2fl, 2fl+1)
    const __half2* h2v = (const __half2*)h2;   // row stride 32
    int beg = rowptr[node];
    int end = rowend[node];
    int deg = end - beg;
    int myidx = (beg + lane < end) ? (int)csr[beg + lane] : 0;
    int window = deg < 64 ? deg : 64;   // wave-uniform
    int npair = window >> 1;
    float ax = 0.0f, ay = 0.0f, bx = 0.0f, by = 0.0f;
    int p = 0;
    for (; p + 7 < npair; p += 8) {          // 16 edges per iteration, 8 loads in flight
        int s0 = __shfl(myidx, 2 * p + half, 64);
        int s1 = __shfl(myidx, 2 * p + 2 + half, 64);
        int s2 = __shfl(myidx, 2 * p + 4 + half, 64);
        int s3 = __shfl(myidx, 2 * p + 6 + half, 64);
        int s4 = __shfl(myidx, 2 * p + 8 + half, 64);
        int s5 = __shfl(myidx, 2 * p + 10 + half, 64);
        int s6 = __shfl(myidx, 2 * p + 12 + half, 64);
        int s7 = __shfl(myidx, 2 * p + 14 + half, 64);
        float2 v0 = __half22float2(h2v[s0 * 32 + fl]);
        float2 v1 = __half22float2(h2v[s1 * 32 + fl]);
        float2 v2 = __half22float2(h2v[s2 * 32 + fl]);
        float2 v3 = __half22float2(h2v[s3 * 32 + fl]);
        float2 v4 = __half22float2(h2v[s4 * 32 + fl]);
        float2 v5 = __half22float2(h2v[s5 * 32 + fl]);
        float2 v6 = __half22float2(h2v[s6 * 32 + fl]);
        float2 v7 = __half22float2(h2v[s7 * 32 + fl]);
        ax += (v0.x + v2.x) + (v4.x + v6.x);
        ay += (v0.y + v2.y) + (v4.y + v6.y);
        bx += (v1.x + v3.x) + (v5.x + v7.x);
        by += (v1.y + v3.y) + (v5.y + v7.y);
    }
    for (; p + 3 < npair; p += 4) {          // 8 edges per iteration
        int s0 = __shfl(myidx, 2 * p + half, 64);
        int s1 = __shfl(myidx, 2 * p + 2 + half, 64);
        int s2 = __shfl(myidx, 2 * p + 4 + half, 64);
        int s3 = __shfl(myidx, 2 * p + 6 + half, 64);
        float2 v0 = __half22float2(h2v[s0 * 32 + fl]);
        float2 v1 = __half22float2(h2v[s1 * 32 + fl]);
        float2 v2 = __half22float2(h2v[s2 * 32 + fl]);
        float2 v3 = __half22float2(h2v[s3 * 32 + fl]);
        ax += v0.x + v2.x;  ay += v0.y + v2.y;
        bx += v1.x + v3.x;  by += v1.y + v3.y;
    }
    for (; p < npair; ++p) {                 // pair tail (uniform trip count)
        int s = __shfl(myidx, 2 * p + half, 64);
        float2 v = __half22float2(h2v[s * 32 + fl]);
        ax += v.x;  ay += v.y;
    }
    if (window & 1) {                        // wave-uniform: all lanes shfl
        int s = __shfl(myidx, window - 1, 64);
        float2 v = __half22float2(h2v[s * 32 + fl]);
        if (half == 0) { ax += v.x;  ay += v.y; }
    }
    if (deg > 64) {                          // rare fallback, direct loads
        int j = beg + 64;
        for (; j + 1 < end; j += 2) {
            int s = csr[j + half];
            float2 v = __half22float2(h2v[s * 32 + fl]);
            ax += v.x;  ay += v.y;
        }
        if (j < end) {
            int s = csr[j];
            float2 v = __half22float2(h2v[s * 32 + fl]);
            if (half == 0) { ax += v.x;  ay += v.y; }
        }
    }
    ax += bx;  ay += by;
    ax += __shfl_xor(ax, 32, 64);            // combine the two half-waves
    ay += __shfl_xor(ay, 32, 64);
    if (half == 0) {
        float nrm = norm[node];
        float2 bs = ((const float2*)bias)[fl];
        float vx = ax * nrm + bs.x;
        float vy = ay * nrm + bs.y;
        float2 o;
        o.x = fmaxf(vx, 0.0f) + log1pf(expf(-fabsf(vx)));
        o.y = fmaxf(vy, 0.0f) + log1pf(expf(-fabsf(vy)));
        ((float2*)out)[node * 32 + fl] = o;
    }
}

extern "C" void kernel_launch(void* const* d_in, const int* in_sizes, int n_in,
                              void* d_out, int out_size, void* d_ws, size_t ws_size,
                              hipStream_t stream) {
    // inputs: t(f32,1), x(f32,N*D), weight(f32,D*D), bias(f32,D), src(i32,E), dst(i32,E)
    const float* x    = (const float*)d_in[1];
    const float* W    = (const float*)d_in[2];
    const float* bias = (const float*)d_in[3];
    const int* src = (const int*)d_in[4];
    const int* dst = (const int*)d_in[5];
    float* out = (float*)d_out;

    // workspace layout (~17.9 MB; poisoned every call — every buffer is
    // fully written before it is read)
    char* ws = (char*)d_ws;
    __half*         h2     = (__half*)(ws);                     // 6.4 MB
    unsigned*       packed = (unsigned*)(ws + 6400000);         // NBUCK*CAP*4 = 7.21 MB
    unsigned short* csr    = (unsigned short*)(ws + 13606912);  // NBUCK*CAP*2 = 3.6 MB
    int*            rowptr = (int*)(ws + 17210368);             // N*4
    int*            rowend = (int*)(ws + 17410368);             // N*4
    float*          norm   = (float*)(ws + 17610368);           // N*4
    int*            cursor = (int*)(ws + 17810368);             // NBUCK*4

    k_init     <<<1, 512, 0, stream>>>(cursor);
    k_bucket   <<<BBLOCKS, BTHREADS, 0, stream>>>(src, dst, cursor, packed);
    k_csr      <<<NBUCK, 1024, 0, stream>>>(cursor, packed, csr, rowptr, rowend, norm);
    k_gemm     <<<(N + 63) / 64, 256, 0, stream>>>(x, W, norm, h2);
    k_aggregate<<<(N + 3) / 4, 256, 0, stream>>>(rowptr, rowend, csr, h2, norm, bias, out);
}